// Round 5
// baseline (84.505 us; speedup 1.0000x reference)
//
#include <hip/hip_runtime.h>
#include <math.h>
#include <stdint.h>

#define BATCH    2048
#define NCHOICES 2048
#define NV       8
#define VS       256
#define KTOT     2048

typedef unsigned short u16;
typedef __attribute__((ext_vector_type(8))) short    bf16x8;
typedef __attribute__((ext_vector_type(8))) u16      u16x8;
typedef __attribute__((ext_vector_type(4))) float    f32x4;

__device__ __forceinline__ u16 f2bf_rne(float x) {
    unsigned u = __float_as_uint(x);
    return (u16)((u + 0x7FFFu + ((u >> 16) & 1u)) >> 16);
}

// ---------------------------------------------------------------------------
// Kernel 1 (fused): bf16 hi/lo split planes + reciprocal sub-vector norms
//                   + sigmoid(nand_weight). One pass over Q and W. (verified)
// ---------------------------------------------------------------------------
__global__ __launch_bounds__(256) void prep_convert(
    const float* __restrict__ Q, const float* __restrict__ W,
    const float* __restrict__ NWT,
    u16* __restrict__ Qh, u16* __restrict__ Ql,
    u16* __restrict__ Wh, u16* __restrict__ Wl,
    float* __restrict__ rq, float* __restrict__ rw, float* __restrict__ snw)
{
    const int row = blockIdx.x;
    const int t   = threadIdx.x;
    const int n   = t >> 5;
    const int l   = t & 31;

    const float* src; u16 *dh, *dl; float* dst;
    if (row < BATCH) {
        src = Q + (size_t)row * KTOT;
        dh = Qh + (size_t)row * KTOT; dl = Ql + (size_t)row * KTOT;
        dst = rq + (size_t)row * NV;
    } else {
        src = W + (size_t)(row - BATCH) * KTOT;
        dh = Wh + (size_t)(row - BATCH) * KTOT; dl = Wl + (size_t)(row - BATCH) * KTOT;
        dst = rw + (size_t)(row - BATCH) * NV;
    }

    const int idx = n * VS + l * 8;
    float4 x0 = *(const float4*)(src + idx);
    float4 x1 = *(const float4*)(src + idx + 4);
    float xs[8] = {x0.x, x0.y, x0.z, x0.w, x1.x, x1.y, x1.z, x1.w};

    u16x8 hv, lv;
    float s = 0.0f;
    #pragma unroll
    for (int j = 0; j < 8; ++j) {
        u16 h = f2bf_rne(xs[j]);
        float hf = __uint_as_float(((unsigned)h) << 16);
        hv[j] = h;
        lv[j] = f2bf_rne(xs[j] - hf);
        s = fmaf(xs[j], xs[j], s);
    }
    *(u16x8*)(dh + idx) = hv;
    *(u16x8*)(dl + idx) = lv;

    #pragma unroll
    for (int m = 1; m < 32; m <<= 1) s += __shfl_xor(s, m, 64);
    if (l == 0) dst[n] = 1.0f / fmaxf(sqrtf(s), 1e-6f);

    if (row >= BATCH && t < NV) {
        const int c = row - BATCH;
        float x = NWT[(size_t)c * NV + t];
        snw[(size_t)c * NV + t] = 1.0f / (1.0f + expf(-x));
    }
}

// ---------------------------------------------------------------------------
// Kernel 2: 8-phase MFMA GEMM, counted-vmcnt pipeline. BM=128, BN=256, BK=32,
// 8 waves (64x64 wave tiles), 3 LDS buffers. v5: ds_read via inline asm so the
// compiler cannot see the gload_lds->ds_read LDS hazard (and thus cannot
// insert vmcnt(0) drains); bare s_barrier / bare waitcnt asm (no "memory"
// clobbers); manual lgkmcnt(0)+sched_barrier(0) per phase (rule #18).
// ---------------------------------------------------------------------------
__device__ __forceinline__ void gload16(const void* g, void* l) {
    __builtin_amdgcn_global_load_lds(
        (__attribute__((address_space(1))) void*)(uintptr_t)g,
        (__attribute__((address_space(3))) void*)(uint32_t)(uintptr_t)l,
        16, 0, 0);
}

// compiler-invisible LDS read: hardware ds_read_b128, no memory operand
__device__ __forceinline__ bf16x8 lds_rd16(const u16* p) {
    f32x4 r;
    asm volatile("ds_read_b128 %0, %1"
                 : "=v"(r)
                 : "v"((uint32_t)(uintptr_t)p));
    return __builtin_bit_cast(bf16x8, r);
}

// swizzled u16 index of logical (row, granule G) in a [rows][32] u16 plane
#define SWZ(R, G) ((R) * 32 + ((((G) ^ (((R) >> 1) & 3))) << 3))

__global__ __launch_bounds__(512, 2) void nand_mfma8(
    const u16* __restrict__ Qh, const u16* __restrict__ Ql,
    const u16* __restrict__ Wh, const u16* __restrict__ Wl,
    const float* __restrict__ rq, const float* __restrict__ rw,
    const float* __restrict__ snw, float* __restrict__ part)
{
    // 3 bufs x [Ah(128x32) | Al | Bh(256x32) | Bl] = 3 x 48 KiB = 144 KiB
    __shared__ __align__(16) u16 L[3][24576];

    const int tid  = threadIdx.x;
    const int lane = tid & 63;
    const int wave = tid >> 6;
    const int wr   = (wave >> 2) * 64;   // 2 wave-rows
    const int wc   = (wave & 3) * 64;    // 4 wave-cols
    const int bm0  = blockIdx.y * 128;
    const int bn0  = blockIdx.x * 256;
    const int z    = blockIdx.z;
    const int kb   = z * 1024;           // this block's K range (32 tiles)

    const int fr = lane & 15;
    const int gi = lane >> 4;
    const int ri = gi * 4;

    // ---- staging geometry: 6 granules (16B) per thread per K-tile ----
    const int gr  = tid >> 2;            // 0..127
    const int gg  = tid & 3;
    const int gsw = (gg ^ ((gr >> 1) & 3)) * 8;   // pre-swizzled k offset

    const u16* sAh  = Qh + (size_t)(bm0 + gr) * KTOT + kb + gsw;
    const u16* sAl  = Ql + (size_t)(bm0 + gr) * KTOT + kb + gsw;
    const u16* sB0h = Wh + (size_t)(bn0 + gr) * KTOT + kb + gsw;
    const u16* sB1h = Wh + (size_t)(bn0 + 128 + gr) * KTOT + kb + gsw;
    const u16* sB0l = Wl + (size_t)(bn0 + gr) * KTOT + kb + gsw;
    const u16* sB1l = Wl + (size_t)(bn0 + 128 + gr) * KTOT + kb + gsw;

    #define STAGE_A(B, T)  do { u16* Lb_ = &L[B][0];                        \
        gload16(sAh  + (T) * 32, Lb_ + tid * 8);                            \
        gload16(sAl  + (T) * 32, Lb_ + 4096  + tid * 8); } while (0)
    #define STAGE_BH(B, T) do { u16* Lb_ = &L[B][0];                        \
        gload16(sB0h + (T) * 32, Lb_ + 8192  + tid * 8);                    \
        gload16(sB1h + (T) * 32, Lb_ + 12288 + tid * 8); } while (0)
    #define STAGE_BL(B, T) do { u16* Lb_ = &L[B][0];                        \
        gload16(sB0l + (T) * 32, Lb_ + 16384 + tid * 8);                    \
        gload16(sB1l + (T) * 32, Lb_ + 20480 + tid * 8); } while (0)

    #define RD_A(M) do {                                                    \
        ah[M] = lds_rd16(Lb + SWZ(wr + (M) * 16 + fr, gi));                 \
        al[M] = lds_rd16(Lb + 4096 + SWZ(wr + (M) * 16 + fr, gi)); } while (0)
    #define RD_B(N) do {                                                    \
        bh[N] = lds_rd16(Lb + 8192  + SWZ(wc + (N) * 16 + fr, gi));         \
        bl[N] = lds_rd16(Lb + 16384 + SWZ(wc + (N) * 16 + fr, gi)); } while (0)

    #define MM(M, N) do {                                                   \
        acc[M][N] = __builtin_amdgcn_mfma_f32_16x16x32_bf16(ah[M], bh[N], acc[M][N], 0, 0, 0); \
        acc[M][N] = __builtin_amdgcn_mfma_f32_16x16x32_bf16(ah[M], bl[N], acc[M][N], 0, 0, 0); \
        acc[M][N] = __builtin_amdgcn_mfma_f32_16x16x32_bf16(al[M], bh[N], acc[M][N], 0, 0, 0); } while (0)

    #define WAIT_LGKM0() do {                                               \
        asm volatile("s_waitcnt lgkmcnt(0)");                               \
        __builtin_amdgcn_sched_barrier(0); } while (0)

    f32x4 prod[4][4];
    #pragma unroll
    for (int m = 0; m < 4; ++m)
        #pragma unroll
        for (int n = 0; n < 4; ++n) prod[m][n] = (f32x4){1.f, 1.f, 1.f, 1.f};

    // prologue: stage tiles 0 and 1; wait tile 0 only (tile 1 stays in flight)
    STAGE_A(0, 0); STAGE_BH(0, 0); STAGE_BL(0, 0);
    STAGE_A(1, 1); STAGE_BH(1, 1); STAGE_BL(1, 1);
    asm volatile("s_waitcnt vmcnt(6)");
    __builtin_amdgcn_s_barrier();

    int buf = 0, bufp = 2;

    #pragma unroll 1
    for (int cc = 0; cc < 4; ++cc) {
        const int chunk = z * 4 + cc;

        // chunk constants (plain loads; retire before first tile boundary)
        float rqv[4][4];
        #pragma unroll
        for (int m = 0; m < 4; ++m)
            #pragma unroll
            for (int i = 0; i < 4; ++i)
                rqv[m][i] = rq[(size_t)(bm0 + wr + m * 16 + ri + i) * NV + chunk];
        float rwv[4], vv[4], uu[4];
        #pragma unroll
        for (int n = 0; n < 4; ++n) {
            const int col = bn0 + wc + n * 16 + fr;
            rwv[n] = rw[(size_t)col * NV + chunk];
            float s = snw[(size_t)col * NV + chunk];
            vv[n] = 2.0f * s - 1.0f;
            uu[n] = 1.0f - s;
        }

        f32x4 acc[4][4];
        #pragma unroll
        for (int m = 0; m < 4; ++m)
            #pragma unroll
            for (int n = 0; n < 4; ++n) acc[m][n] = (f32x4){0.f, 0.f, 0.f, 0.f};

        #pragma unroll 1
        for (int t8 = 0; t8 < 8; ++t8) {
            const int t = cc * 8 + t8;
            const u16* Lb = &L[buf][0];
            const bool pf = (t + 2) < 32;

            bf16x8 ah[4], al[4], bh[4], bl[4];

            // phase 1: A01+B01 reads | stage A(t+2) | Q1 = m01 x n01
            RD_A(0); RD_A(1); RD_B(0); RD_B(1);
            if (pf) STAGE_A(bufp, t + 2);
            __builtin_amdgcn_s_barrier();
            WAIT_LGKM0();
            __builtin_amdgcn_s_setprio(1);
            MM(0, 0); MM(0, 1); MM(1, 0); MM(1, 1);
            __builtin_amdgcn_s_setprio(0);
            __builtin_amdgcn_s_barrier();

            // phase 2: B23 reads | stage Bh(t+2) | Q2 = m01 x n23
            RD_B(2); RD_B(3);
            if (pf) STAGE_BH(bufp, t + 2);
            __builtin_amdgcn_s_barrier();
            WAIT_LGKM0();
            __builtin_amdgcn_s_setprio(1);
            MM(0, 2); MM(0, 3); MM(1, 2); MM(1, 3);
            __builtin_amdgcn_s_setprio(0);
            __builtin_amdgcn_s_barrier();

            // phase 3: A23 reads | stage Bl(t+2) | Q3 = m23 x n23
            RD_A(2); RD_A(3);
            if (pf) STAGE_BL(bufp, t + 2);
            __builtin_amdgcn_s_barrier();
            WAIT_LGKM0();
            __builtin_amdgcn_s_setprio(1);
            MM(2, 2); MM(2, 3); MM(3, 2); MM(3, 3);
            __builtin_amdgcn_s_setprio(0);
            __builtin_amdgcn_s_barrier();

            // phase 4: Q4 = m23 x n01 (operands held in registers)
            __builtin_amdgcn_s_setprio(1);
            MM(2, 0); MM(2, 1); MM(3, 0); MM(3, 1);
            __builtin_amdgcn_s_setprio(0);

            // tile boundary: counted wait — tile t+1's 6 loads must be done;
            // tile t+2's 6 (issued this tile) stay in flight.
            if (t < 30) {
                asm volatile("s_waitcnt vmcnt(6)");
                __builtin_amdgcn_s_barrier();
            } else if (t == 30) {
                asm volatile("s_waitcnt vmcnt(0)");
                __builtin_amdgcn_s_barrier();
            }
            buf  = (buf  == 2) ? 0 : buf  + 1;
            bufp = (bufp == 2) ? 0 : bufp + 1;
        }

        // chunk epilogue: cos -> leaky -> interpolate -> running product
        #pragma unroll
        for (int m = 0; m < 4; ++m)
            #pragma unroll
            for (int i = 0; i < 4; ++i)
                #pragma unroll
                for (int n = 0; n < 4; ++n) {
                    float cosv = acc[m][n][i] * rqv[m][i] * rwv[n];
                    float Lk = fmaxf(cosv, 0.01f * cosv);
                    prod[m][n][i] *= fmaf(Lk, vv[n], uu[n]);
                }
    }

    float* P = part + (size_t)z * BATCH * NCHOICES;
    #pragma unroll
    for (int m = 0; m < 4; ++m)
        #pragma unroll
        for (int i = 0; i < 4; ++i) {
            const int row = bm0 + wr + m * 16 + ri + i;
            float* pr = P + (size_t)row * NCHOICES + bn0 + wc + fr;
            #pragma unroll
            for (int n = 0; n < 4; ++n) pr[n * 16] = prod[m][n][i];
        }

    #undef STAGE_A
    #undef STAGE_BH
    #undef STAGE_BL
    #undef RD_A
    #undef RD_B
    #undef MM
    #undef WAIT_LGKM0
}

// ---------------------------------------------------------------------------
// Kernel 3: combine 2 split-K partial products.
// ---------------------------------------------------------------------------
__global__ __launch_bounds__(256) void combine_kernel(
    const float* __restrict__ p, float* __restrict__ out)
{
    const size_t NN = (size_t)BATCH * NCHOICES;
    size_t i = ((size_t)blockIdx.x * 256 + threadIdx.x) * 4;
    float4 a = *(const float4*)(p + i);
    float4 b = *(const float4*)(p + NN + i);
    float4 o;
    o.x = a.x * b.x;
    o.y = a.y * b.y;
    o.z = a.z * b.z;
    o.w = a.w * b.w;
    *(float4*)(out + i) = o;
}

// ---------------------------------------------------------------------------
// Fallback: R1's verified fp32 vector-FMA path (used if ws too small).
// ---------------------------------------------------------------------------
__global__ __launch_bounds__(256) void prep_kernel(
    const float* __restrict__ Q, const float* __restrict__ W,
    const float* __restrict__ NWT,
    float* __restrict__ rq, float* __restrict__ rw, float* __restrict__ snw)
{
    const int row = blockIdx.x;
    const int t   = threadIdx.x;
    const int n   = t >> 5;
    const int l   = t & 31;

    const float* src; float* dst;
    if (row < BATCH) { src = Q + (size_t)row * KTOT; dst = rq + (size_t)row * NV; }
    else { src = W + (size_t)(row - BATCH) * KTOT; dst = rw + (size_t)(row - BATCH) * NV; }

    const float* v = src + n * VS + l * 8;
    float4 a = *(const float4*)(v);
    float4 b = *(const float4*)(v + 4);
    float s = a.x*a.x + a.y*a.y + a.z*a.z + a.w*a.w
            + b.x*b.x + b.y*b.y + b.z*b.z + b.w*b.w;
    #pragma unroll
    for (int m = 1; m < 32; m <<= 1) s += __shfl_xor(s, m, 64);
    if (l == 0) dst[n] = 1.0f / fmaxf(sqrtf(s), 1e-6f);
    if (row >= BATCH && t < NV) {
        const int c = row - BATCH;
        float x = NWT[(size_t)c * NV + t];
        snw[(size_t)c * NV + t] = 1.0f / (1.0f + expf(-x));
    }
}

__global__ __launch_bounds__(256, 2) void nand_gemm(
    const float* __restrict__ Q, const float* __restrict__ W,
    const float* __restrict__ rq, const float* __restrict__ rw,
    const float* __restrict__ snw, float* __restrict__ out)
{
    __shared__ __align__(16) float As[16][128 + 4];
    __shared__ __align__(16) float Bs[16][128 + 4];
    __shared__ __align__(16) float rqs[128];
    __shared__ __align__(16) float rws[128];
    __shared__ __align__(16) float sns[128];

    const int tid = threadIdx.x;
    const int tx  = tid & 15;
    const int ty  = tid >> 4;
    const int bm0 = blockIdx.y * 128;
    const int bn0 = blockIdx.x * 128;
    const int lr  = tid >> 2;
    const int lk  = (tid & 3) * 4;

    float prod[8][8];
    #pragma unroll
    for (int i = 0; i < 8; ++i)
        #pragma unroll
        for (int j = 0; j < 8; ++j) prod[i][j] = 1.0f;

    for (int n = 0; n < NV; ++n) {
        float acc[8][8];
        #pragma unroll
        for (int i = 0; i < 8; ++i)
            #pragma unroll
            for (int j = 0; j < 8; ++j) acc[i][j] = 0.0f;

        #pragma unroll 1
        for (int kt = 0; kt < VS / 16; ++kt) {
            const int k0 = n * VS + kt * 16;
            __syncthreads();
            {
                const float* qrow = Q + (size_t)(bm0 + lr) * KTOT + k0 + lk;
                float4 a0 = *(const float4*)(qrow);
                float4 a1 = *(const float4*)(qrow + (size_t)64 * KTOT);
                As[lk + 0][lr] = a0.x; As[lk + 1][lr] = a0.y;
                As[lk + 2][lr] = a0.z; As[lk + 3][lr] = a0.w;
                As[lk + 0][64 + lr] = a1.x; As[lk + 1][64 + lr] = a1.y;
                As[lk + 2][64 + lr] = a1.z; As[lk + 3][64 + lr] = a1.w;

                const float* wrow = W + (size_t)(bn0 + lr) * KTOT + k0 + lk;
                float4 b0 = *(const float4*)(wrow);
                float4 b1 = *(const float4*)(wrow + (size_t)64 * KTOT);
                Bs[lk + 0][lr] = b0.x; Bs[lk + 1][lr] = b0.y;
                Bs[lk + 2][lr] = b0.z; Bs[lk + 3][lr] = b0.w;
                Bs[lk + 0][64 + lr] = b1.x; Bs[lk + 1][64 + lr] = b1.y;
                Bs[lk + 2][64 + lr] = b1.z; Bs[lk + 3][64 + lr] = b1.w;
            }
            if (kt == 0) {
                for (int i = tid; i < 3 * 128; i += 256) {
                    if (i < 128)      rqs[i]       = rq[(size_t)(bm0 + i) * NV + n];
                    else if (i < 256) rws[i - 128] = rw[(size_t)(bn0 + i - 128) * NV + n];
                    else              sns[i - 256] = snw[(size_t)(bn0 + i - 256) * NV + n];
                }
            }
            __syncthreads();

            #pragma unroll
            for (int kk = 0; kk < 16; ++kk) {
                float4 a0 = *(const float4*)&As[kk][ty * 4];
                float4 a1 = *(const float4*)&As[kk][64 + ty * 4];
                float4 b0 = *(const float4*)&Bs[kk][tx * 4];
                float4 b1 = *(const float4*)&Bs[kk][64 + tx * 4];
                float ar[8] = {a0.x, a0.y, a0.z, a0.w, a1.x, a1.y, a1.z, a1.w};
                float br[8] = {b0.x, b0.y, b0.z, b0.w, b1.x, b1.y, b1.z, b1.w};
                #pragma unroll
                for (int i = 0; i < 8; ++i)
                    #pragma unroll
                    for (int j = 0; j < 8; ++j)
                        acc[i][j] = fmaf(ar[i], br[j], acc[i][j]);
            }
        }

        float rwv[8], uu[8], vv[8];
        #pragma unroll
        for (int j = 0; j < 8; ++j) {
            int cc = (j < 4) ? (tx * 4 + j) : (64 + tx * 4 + (j - 4));
            rwv[j] = rws[cc];
            float s = sns[cc];
            uu[j] = 1.0f - s;
            vv[j] = 2.0f * s - 1.0f;
        }
        #pragma unroll
        for (int i = 0; i < 8; ++i) {
            int r = (i < 4) ? (ty * 4 + i) : (64 + ty * 4 + (i - 4));
            float rqv = rqs[r];
            #pragma unroll
            for (int j = 0; j < 8; ++j) {
                float cosv = acc[i][j] * rqv * rwv[j];
                float Lk = fmaxf(cosv, 0.01f * cosv);
                prod[i][j] *= fmaf(Lk, vv[j], uu[j]);
            }
        }
    }

    #pragma unroll
    for (int i = 0; i < 8; ++i) {
        int r = (i < 4) ? (ty * 4 + i) : (64 + ty * 4 + (i - 4));
        float* orow = out + (size_t)(bm0 + r) * NCHOICES + bn0;
        float4 o0 = {prod[i][0], prod[i][1], prod[i][2], prod[i][3]};
        float4 o1 = {prod[i][4], prod[i][5], prod[i][6], prod[i][7]};
        *(float4*)(orow + tx * 4)      = o0;
        *(float4*)(orow + 64 + tx * 4) = o1;
    }
}

extern "C" void kernel_launch(void* const* d_in, const int* in_sizes, int n_in,
                              void* d_out, int out_size, void* d_ws, size_t ws_size,
                              hipStream_t stream)
{
    const float* Q   = (const float*)d_in[0];
    const float* W   = (const float*)d_in[1];
    const float* NWT = (const float*)d_in[2];
    float* out = (float*)d_out;

    char* w = (char*)d_ws;
    float* rq  = (float*)w; w += (size_t)BATCH    * NV * 4;
    float* rwn = (float*)w; w += (size_t)NCHOICES * NV * 4;
    float* snw = (float*)w; w += (size_t)NCHOICES * NV * 4;
    u16* Qh = (u16*)w; w += (size_t)BATCH * KTOT * 2;
    u16* Ql = (u16*)w; w += (size_t)BATCH * KTOT * 2;
    u16* Wh = (u16*)w; w += (size_t)NCHOICES * KTOT * 2;
    u16* Wl = (u16*)w; w += (size_t)NCHOICES * KTOT * 2;
    float* part = (float*)w; w += (size_t)2 * BATCH * NCHOICES * 4;
    const size_t needed = (size_t)(w - (char*)d_ws);

    if (ws_size >= needed) {
        prep_convert<<<BATCH + NCHOICES, 256, 0, stream>>>(
            Q, W, NWT, Qh, Ql, Wh, Wl, rq, rwn, snw);
        dim3 grid(NCHOICES / 256, BATCH / 128, 2);
        nand_mfma8<<<grid, 512, 0, stream>>>(Qh, Ql, Wh, Wl, rq, rwn, snw, part);
        combine_kernel<<<(BATCH * NCHOICES / 4) / 256, 256, 0, stream>>>(part, out);
    } else {
        prep_kernel<<<BATCH + NCHOICES, 256, 0, stream>>>(Q, W, NWT, rq, rwn, snw);
        dim3 grid(NCHOICES / 128, BATCH / 128);
        nand_gemm<<<grid, 256, 0, stream>>>(Q, W, rq, rwn, snw, out);
    }
}

// Round 6
// 83.240 us; speedup vs baseline: 1.0152x; 1.0152x over previous
//
#include <hip/hip_runtime.h>
#include <math.h>
#include <stdint.h>

#define BATCH    2048
#define NCHOICES 2048
#define NV       8
#define VS       256
#define KTOT     2048

typedef unsigned short u16;
typedef __attribute__((ext_vector_type(8))) short    bf16x8;
typedef __attribute__((ext_vector_type(8))) u16      u16x8;
typedef __attribute__((ext_vector_type(4))) float    f32x4;

__device__ __forceinline__ u16 f2bf_rne(float x) {
    unsigned u = __float_as_uint(x);
    return (u16)((u + 0x7FFFu + ((u >> 16) & 1u)) >> 16);
}

// ---------------------------------------------------------------------------
// Kernel 1 (fused): bf16 hi/lo split planes + reciprocal sub-vector norms
//                   + sigmoid(nand_weight). One pass over Q and W. (verified)
// ---------------------------------------------------------------------------
__global__ __launch_bounds__(256) void prep_convert(
    const float* __restrict__ Q, const float* __restrict__ W,
    const float* __restrict__ NWT,
    u16* __restrict__ Qh, u16* __restrict__ Ql,
    u16* __restrict__ Wh, u16* __restrict__ Wl,
    float* __restrict__ rq, float* __restrict__ rw, float* __restrict__ snw)
{
    const int row = blockIdx.x;
    const int t   = threadIdx.x;
    const int n   = t >> 5;
    const int l   = t & 31;

    const float* src; u16 *dh, *dl; float* dst;
    if (row < BATCH) {
        src = Q + (size_t)row * KTOT;
        dh = Qh + (size_t)row * KTOT; dl = Ql + (size_t)row * KTOT;
        dst = rq + (size_t)row * NV;
    } else {
        src = W + (size_t)(row - BATCH) * KTOT;
        dh = Wh + (size_t)(row - BATCH) * KTOT; dl = Wl + (size_t)(row - BATCH) * KTOT;
        dst = rw + (size_t)(row - BATCH) * NV;
    }

    const int idx = n * VS + l * 8;
    float4 x0 = *(const float4*)(src + idx);
    float4 x1 = *(const float4*)(src + idx + 4);
    float xs[8] = {x0.x, x0.y, x0.z, x0.w, x1.x, x1.y, x1.z, x1.w};

    u16x8 hv, lv;
    float s = 0.0f;
    #pragma unroll
    for (int j = 0; j < 8; ++j) {
        u16 h = f2bf_rne(xs[j]);
        float hf = __uint_as_float(((unsigned)h) << 16);
        hv[j] = h;
        lv[j] = f2bf_rne(xs[j] - hf);
        s = fmaf(xs[j], xs[j], s);
    }
    *(u16x8*)(dh + idx) = hv;
    *(u16x8*)(dl + idx) = lv;

    #pragma unroll
    for (int m = 1; m < 32; m <<= 1) s += __shfl_xor(s, m, 64);
    if (l == 0) dst[n] = 1.0f / fmaxf(sqrtf(s), 1e-6f);

    if (row >= BATCH && t < NV) {
        const int c = row - BATCH;
        float x = NWT[(size_t)c * NV + t];
        snw[(size_t)c * NV + t] = 1.0f / (1.0f + expf(-x));
    }
}

// ---------------------------------------------------------------------------
// Kernel 2: MFMA GEMM v6. BM=BN=128, BK=32, 4 waves (64x64 wave tiles),
// 2 LDS buffers (64 KiB/block -> 2 blocks/CU), grid 16x16x2 = 512 blocks.
// One barrier per K-tile; cross-block overlap hides LDS/stage/barrier time.
// 3-pass bf16 split; fused per-chunk epilogue + running product. Split-K x2.
// ---------------------------------------------------------------------------
__device__ __forceinline__ void gload16(const void* g, void* l) {
    __builtin_amdgcn_global_load_lds(
        (__attribute__((address_space(1))) void*)(uintptr_t)g,
        (__attribute__((address_space(3))) void*)(uint32_t)(uintptr_t)l,
        16, 0, 0);
}

// compiler-invisible LDS read: hardware ds_read_b128, no memory operand
__device__ __forceinline__ bf16x8 lds_rd16(const u16* p) {
    f32x4 r;
    asm volatile("ds_read_b128 %0, %1"
                 : "=v"(r)
                 : "v"((uint32_t)(uintptr_t)p));
    return __builtin_bit_cast(bf16x8, r);
}

// swizzled u16 index of logical (row, granule G) in a [128][32] u16 plane
#define SWZ(R, G) ((R) * 32 + ((((G) ^ (((R) >> 1) & 3))) << 3))

__global__ __launch_bounds__(256, 2) void nand_mfma2b(
    const u16* __restrict__ Qh, const u16* __restrict__ Ql,
    const u16* __restrict__ Wh, const u16* __restrict__ Wl,
    const float* __restrict__ rq, const float* __restrict__ rw,
    const float* __restrict__ snw, float* __restrict__ part)
{
    // 2 bufs x [Ah(128x32) | Al | Bh | Bl] = 2 x 32 KiB = 64 KiB
    __shared__ __align__(16) u16 L[2][16384];

    const int tid  = threadIdx.x;
    const int lane = tid & 63;
    const int wave = tid >> 6;           // 0..3
    const int wr   = (wave >> 1) * 64;
    const int wc   = (wave & 1) * 64;
    const int bm0  = blockIdx.y * 128;
    const int bn0  = blockIdx.x * 128;
    const int z    = blockIdx.z;
    const int kb   = z * 1024;           // this block's K range (32 tiles)

    const int fr = lane & 15;
    const int gi = lane >> 4;
    const int ri = gi * 4;

    // ---- staging geometry: 8 x 16B granules / thread / K-tile ----
    // plane granule index G = wave*128 + load*64 + lane; logical row = G>>2,
    // col granule = G&3, source col pre-swizzled: sw dep. on lane only.
    const int lr = lane >> 2;                                 // 0..15
    const int sw = 8 * ((lane & 3) ^ ((lane >> 3) & 3));      // pre-swizzle
    const int r0 = wave * 32 + lr;                            // load-0 row
    const int r1 = r0 + 16;                                   // load-1 row

    const u16* sAh0 = Qh + (size_t)(bm0 + r0) * KTOT + kb + sw;
    const u16* sAh1 = Qh + (size_t)(bm0 + r1) * KTOT + kb + sw;
    const u16* sAl0 = Ql + (size_t)(bm0 + r0) * KTOT + kb + sw;
    const u16* sAl1 = Ql + (size_t)(bm0 + r1) * KTOT + kb + sw;
    const u16* sBh0 = Wh + (size_t)(bn0 + r0) * KTOT + kb + sw;
    const u16* sBh1 = Wh + (size_t)(bn0 + r1) * KTOT + kb + sw;
    const u16* sBl0 = Wl + (size_t)(bn0 + r0) * KTOT + kb + sw;
    const u16* sBl1 = Wl + (size_t)(bn0 + r1) * KTOT + kb + sw;

    // dest (u16 units): plane*4096 + wave*1024 + load*512 (+ lane*8 by HW)
    #define STAGE(B, T) do { u16* Lb_ = &L[B][0]; const int ko = (T) * 32;   \
        gload16(sAh0 + ko, Lb_ + wave * 1024);                               \
        gload16(sAh1 + ko, Lb_ + wave * 1024 + 512);                         \
        gload16(sAl0 + ko, Lb_ + 4096  + wave * 1024);                       \
        gload16(sAl1 + ko, Lb_ + 4096  + wave * 1024 + 512);                 \
        gload16(sBh0 + ko, Lb_ + 8192  + wave * 1024);                       \
        gload16(sBh1 + ko, Lb_ + 8192  + wave * 1024 + 512);                 \
        gload16(sBl0 + ko, Lb_ + 12288 + wave * 1024);                       \
        gload16(sBl1 + ko, Lb_ + 12288 + wave * 1024 + 512);                 \
    } while (0)

    #define RD_A(M) do {                                                    \
        ah[M] = lds_rd16(Lb + SWZ(wr + (M) * 16 + fr, gi));                  \
        al[M] = lds_rd16(Lb + 4096 + SWZ(wr + (M) * 16 + fr, gi)); } while (0)
    #define RD_B(N) do {                                                    \
        bh[N] = lds_rd16(Lb + 8192  + SWZ(wc + (N) * 16 + fr, gi));          \
        bl[N] = lds_rd16(Lb + 12288 + SWZ(wc + (N) * 16 + fr, gi)); } while (0)

    #define MM(M, N) do {                                                   \
        acc[M][N] = __builtin_amdgcn_mfma_f32_16x16x32_bf16(ah[M], bh[N], acc[M][N], 0, 0, 0); \
        acc[M][N] = __builtin_amdgcn_mfma_f32_16x16x32_bf16(ah[M], bl[N], acc[M][N], 0, 0, 0); \
        acc[M][N] = __builtin_amdgcn_mfma_f32_16x16x32_bf16(al[M], bh[N], acc[M][N], 0, 0, 0); } while (0)

    f32x4 prod[4][4];
    #pragma unroll
    for (int m = 0; m < 4; ++m)
        #pragma unroll
        for (int n = 0; n < 4; ++n) prod[m][n] = (f32x4){1.f, 1.f, 1.f, 1.f};

    // prologue: stage tile 0, drain, barrier
    STAGE(0, 0);
    asm volatile("s_waitcnt vmcnt(0)");
    __builtin_amdgcn_s_barrier();

    int buf = 0;

    #pragma unroll 1
    for (int cc = 0; cc < 4; ++cc) {
        const int chunk = z * 4 + cc;

        f32x4 acc[4][4];
        #pragma unroll
        for (int m = 0; m < 4; ++m)
            #pragma unroll
            for (int n = 0; n < 4; ++n) acc[m][n] = (f32x4){0.f, 0.f, 0.f, 0.f};

        #pragma unroll 1
        for (int t8 = 0; t8 < 8; ++t8) {
            const int t = cc * 8 + t8;
            const u16* Lb = &L[buf][0];

            // issue next-tile stage FIRST (overlaps reads + MFMA below)
            if (t + 1 < 32) STAGE(buf ^ 1, t + 1);

            bf16x8 ah[4], al[4], bh[4], bl[4];
            RD_A(0); RD_A(1); RD_A(2); RD_A(3);
            RD_B(0); RD_B(1); RD_B(2); RD_B(3);
            asm volatile("s_waitcnt lgkmcnt(0)");
            __builtin_amdgcn_sched_barrier(0);

            __builtin_amdgcn_s_setprio(1);
            MM(0, 0); MM(0, 1); MM(1, 0); MM(1, 1);
            MM(0, 2); MM(0, 3); MM(1, 2); MM(1, 3);
            MM(2, 2); MM(2, 3); MM(3, 2); MM(3, 3);
            MM(2, 0); MM(2, 1); MM(3, 0); MM(3, 1);
            __builtin_amdgcn_s_setprio(0);

            // single sync point per K-tile: next buffer staged + all reads
            // of current buffer already consumed (lgkmcnt(0) above).
            asm volatile("s_waitcnt vmcnt(0)");
            __builtin_amdgcn_s_barrier();
            buf ^= 1;
        }

        // chunk epilogue: constants loaded HERE (keeps hot-loop regs low)
        float rwv[4], vv[4], uu[4];
        #pragma unroll
        for (int n = 0; n < 4; ++n) {
            const int col = bn0 + wc + n * 16 + fr;
            rwv[n] = rw[(size_t)col * NV + chunk];
            float s = snw[(size_t)col * NV + chunk];
            vv[n] = 2.0f * s - 1.0f;
            uu[n] = 1.0f - s;
        }
        #pragma unroll
        for (int m = 0; m < 4; ++m) {
            #pragma unroll
            for (int i = 0; i < 4; ++i) {
                const float rqv =
                    rq[(size_t)(bm0 + wr + m * 16 + ri + i) * NV + chunk];
                #pragma unroll
                for (int n = 0; n < 4; ++n) {
                    float cosv = acc[m][n][i] * rqv * rwv[n];
                    float Lk = fmaxf(cosv, 0.01f * cosv);
                    prod[m][n][i] *= fmaf(Lk, vv[n], uu[n]);
                }
            }
        }
    }

    float* P = part + (size_t)z * BATCH * NCHOICES;
    #pragma unroll
    for (int m = 0; m < 4; ++m)
        #pragma unroll
        for (int i = 0; i < 4; ++i) {
            const int row = bm0 + wr + m * 16 + ri + i;
            float* pr = P + (size_t)row * NCHOICES + bn0 + wc + fr;
            #pragma unroll
            for (int n = 0; n < 4; ++n) pr[n * 16] = prod[m][n][i];
        }

    #undef STAGE
    #undef RD_A
    #undef RD_B
    #undef MM
}

// ---------------------------------------------------------------------------
// Kernel 3: combine 2 split-K partial products.
// ---------------------------------------------------------------------------
__global__ __launch_bounds__(256) void combine_kernel(
    const float* __restrict__ p, float* __restrict__ out)
{
    const size_t NN = (size_t)BATCH * NCHOICES;
    size_t i = ((size_t)blockIdx.x * 256 + threadIdx.x) * 4;
    float4 a = *(const float4*)(p + i);
    float4 b = *(const float4*)(p + NN + i);
    float4 o;
    o.x = a.x * b.x;
    o.y = a.y * b.y;
    o.z = a.z * b.z;
    o.w = a.w * b.w;
    *(float4*)(out + i) = o;
}

// ---------------------------------------------------------------------------
// Fallback: R1's verified fp32 vector-FMA path (used if ws too small).
// ---------------------------------------------------------------------------
__global__ __launch_bounds__(256) void prep_kernel(
    const float* __restrict__ Q, const float* __restrict__ W,
    const float* __restrict__ NWT,
    float* __restrict__ rq, float* __restrict__ rw, float* __restrict__ snw)
{
    const int row = blockIdx.x;
    const int t   = threadIdx.x;
    const int n   = t >> 5;
    const int l   = t & 31;

    const float* src; float* dst;
    if (row < BATCH) { src = Q + (size_t)row * KTOT; dst = rq + (size_t)row * NV; }
    else { src = W + (size_t)(row - BATCH) * KTOT; dst = rw + (size_t)(row - BATCH) * NV; }

    const float* v = src + n * VS + l * 8;
    float4 a = *(const float4*)(v);
    float4 b = *(const float4*)(v + 4);
    float s = a.x*a.x + a.y*a.y + a.z*a.z + a.w*a.w
            + b.x*b.x + b.y*b.y + b.z*b.z + b.w*b.w;
    #pragma unroll
    for (int m = 1; m < 32; m <<= 1) s += __shfl_xor(s, m, 64);
    if (l == 0) dst[n] = 1.0f / fmaxf(sqrtf(s), 1e-6f);
    if (row >= BATCH && t < NV) {
        const int c = row - BATCH;
        float x = NWT[(size_t)c * NV + t];
        snw[(size_t)c * NV + t] = 1.0f / (1.0f + expf(-x));
    }
}

__global__ __launch_bounds__(256, 2) void nand_gemm(
    const float* __restrict__ Q, const float* __restrict__ W,
    const float* __restrict__ rq, const float* __restrict__ rw,
    const float* __restrict__ snw, float* __restrict__ out)
{
    __shared__ __align__(16) float As[16][128 + 4];
    __shared__ __align__(16) float Bs[16][128 + 4];
    __shared__ __align__(16) float rqs[128];
    __shared__ __align__(16) float rws[128];
    __shared__ __align__(16) float sns[128];

    const int tid = threadIdx.x;
    const int tx  = tid & 15;
    const int ty  = tid >> 4;
    const int bm0 = blockIdx.y * 128;
    const int bn0 = blockIdx.x * 128;
    const int lr  = tid >> 2;
    const int lk  = (tid & 3) * 4;

    float prod[8][8];
    #pragma unroll
    for (int i = 0; i < 8; ++i)
        #pragma unroll
        for (int j = 0; j < 8; ++j) prod[i][j] = 1.0f;

    for (int n = 0; n < NV; ++n) {
        float acc[8][8];
        #pragma unroll
        for (int i = 0; i < 8; ++i)
            #pragma unroll
            for (int j = 0; j < 8; ++j) acc[i][j] = 0.0f;

        #pragma unroll 1
        for (int kt = 0; kt < VS / 16; ++kt) {
            const int k0 = n * VS + kt * 16;
            __syncthreads();
            {
                const float* qrow = Q + (size_t)(bm0 + lr) * KTOT + k0 + lk;
                float4 a0 = *(const float4*)(qrow);
                float4 a1 = *(const float4*)(qrow + (size_t)64 * KTOT);
                As[lk + 0][lr] = a0.x; As[lk + 1][lr] = a0.y;
                As[lk + 2][lr] = a0.z; As[lk + 3][lr] = a0.w;
                As[lk + 0][64 + lr] = a1.x; As[lk + 1][64 + lr] = a1.y;
                As[lk + 2][64 + lr] = a1.z; As[lk + 3][64 + lr] = a1.w;

                const float* wrow = W + (size_t)(bn0 + lr) * KTOT + k0 + lk;
                float4 b0 = *(const float4*)(wrow);
                float4 b1 = *(const float4*)(wrow + (size_t)64 * KTOT);
                Bs[lk + 0][lr] = b0.x; Bs[lk + 1][lr] = b0.y;
                Bs[lk + 2][lr] = b0.z; Bs[lk + 3][lr] = b0.w;
                Bs[lk + 0][64 + lr] = b1.x; Bs[lk + 1][64 + lr] = b1.y;
                Bs[lk + 2][64 + lr] = b1.z; Bs[lk + 3][64 + lr] = b1.w;
            }
            if (kt == 0) {
                for (int i = tid; i < 3 * 128; i += 256) {
                    if (i < 128)      rqs[i]       = rq[(size_t)(bm0 + i) * NV + n];
                    else if (i < 256) rws[i - 128] = rw[(size_t)(bn0 + i - 128) * NV + n];
                    else              sns[i - 256] = snw[(size_t)(bn0 + i - 256) * NV + n];
                }
            }
            __syncthreads();

            #pragma unroll
            for (int kk = 0; kk < 16; ++kk) {
                float4 a0 = *(const float4*)&As[kk][ty * 4];
                float4 a1 = *(const float4*)&As[kk][64 + ty * 4];
                float4 b0 = *(const float4*)&Bs[kk][tx * 4];
                float4 b1 = *(const float4*)&Bs[kk][64 + tx * 4];
                float ar[8] = {a0.x, a0.y, a0.z, a0.w, a1.x, a1.y, a1.z, a1.w};
                float br[8] = {b0.x, b0.y, b0.z, b0.w, b1.x, b1.y, b1.z, b1.w};
                #pragma unroll
                for (int i = 0; i < 8; ++i)
                    #pragma unroll
                    for (int j = 0; j < 8; ++j)
                        acc[i][j] = fmaf(ar[i], br[j], acc[i][j]);
            }
        }

        float rwv[8], uu[8], vv[8];
        #pragma unroll
        for (int j = 0; j < 8; ++j) {
            int cc = (j < 4) ? (tx * 4 + j) : (64 + tx * 4 + (j - 4));
            rwv[j] = rws[cc];
            float s = sns[cc];
            uu[j] = 1.0f - s;
            vv[j] = 2.0f * s - 1.0f;
        }
        #pragma unroll
        for (int i = 0; i < 8; ++i) {
            int r = (i < 4) ? (ty * 4 + i) : (64 + ty * 4 + (i - 4));
            float rqv = rqs[r];
            #pragma unroll
            for (int j = 0; j < 8; ++j) {
                float cosv = acc[i][j] * rqv * rwv[j];
                float Lk = fmaxf(cosv, 0.01f * cosv);
                prod[i][j] *= fmaf(Lk, vv[j], uu[j]);
            }
        }
    }

    #pragma unroll
    for (int i = 0; i < 8; ++i) {
        int r = (i < 4) ? (ty * 4 + i) : (64 + ty * 4 + (i - 4));
        float* orow = out + (size_t)(bm0 + r) * NCHOICES + bn0;
        float4 o0 = {prod[i][0], prod[i][1], prod[i][2], prod[i][3]};
        float4 o1 = {prod[i][4], prod[i][5], prod[i][6], prod[i][7]};
        *(float4*)(orow + tx * 4)      = o0;
        *(float4*)(orow + 64 + tx * 4) = o1;
    }
}

extern "C" void kernel_launch(void* const* d_in, const int* in_sizes, int n_in,
                              void* d_out, int out_size, void* d_ws, size_t ws_size,
                              hipStream_t stream)
{
    const float* Q   = (const float*)d_in[0];
    const float* W   = (const float*)d_in[1];
    const float* NWT = (const float*)d_in[2];
    float* out = (float*)d_out;

    char* w = (char*)d_ws;
    float* rq  = (float*)w; w += (size_t)BATCH    * NV * 4;
    float* rwn = (float*)w; w += (size_t)NCHOICES * NV * 4;
    float* snw = (float*)w; w += (size_t)NCHOICES * NV * 4;
    u16* Qh = (u16*)w; w += (size_t)BATCH * KTOT * 2;
    u16* Ql = (u16*)w; w += (size_t)BATCH * KTOT * 2;
    u16* Wh = (u16*)w; w += (size_t)NCHOICES * KTOT * 2;
    u16* Wl = (u16*)w; w += (size_t)NCHOICES * KTOT * 2;
    float* part = (float*)w; w += (size_t)2 * BATCH * NCHOICES * 4;
    const size_t needed = (size_t)(w - (char*)d_ws);

    if (ws_size >= needed) {
        prep_convert<<<BATCH + NCHOICES, 256, 0, stream>>>(
            Q, W, NWT, Qh, Ql, Wh, Wl, rq, rwn, snw);
        dim3 grid(NCHOICES / 128, BATCH / 128, 2);
        nand_mfma2b<<<grid, 256, 0, stream>>>(Qh, Ql, Wh, Wl, rq, rwn, snw, part);
        combine_kernel<<<(BATCH * NCHOICES / 4) / 256, 256, 0, stream>>>(part, out);
    } else {
        prep_kernel<<<BATCH + NCHOICES, 256, 0, stream>>>(Q, W, NWT, rq, rwn, snw);
        dim3 grid(NCHOICES / 128, BATCH / 128);
        nand_gemm<<<grid, 256, 0, stream>>>(Q, W, rq, rwn, snw, out);
    }
}